// Round 1
// baseline (5203.543 us; speedup 1.0000x reference)
//
#include <hip/hip_runtime.h>
#include <hip/hip_bf16.h>

#define EPS 1e-8f

// ---- workspace layout (float offsets) ----
#define OF_FLAG   0L          // int flag: 0=f32 inputs, 1=bf16 inputs
#define OF_THETA  16L         // [B=4][66]
#define OF_TPF    512L        // tp as f32 [64][64]
#define OF_SPF    4608L       // sp as f32 [512][512]
#define OF_XF     266752L     // x as f32 [64][32768]
#define OF_MI0    2363904L    // [i=0..10][slice=0..63][32768]  (later overwritten with chain partial sums)
#define OF_SCAL   25432576L   // scalars: rinv0[64] @+0 ; d1 @+64+(i-1)*64 ; d2 @+704+... ; nrm @+1344+...
#define OF_RST    25434624L   // [64][32768] s-step matmul scratch
// total = 27531776 floats = 110.1 MB

__device__ inline float ld_in(const void* p, long i, int bf) {
  if (bf) return __bfloat162float(((const __hip_bfloat16*)p)[i]);
  return ((const float*)p)[i];
}

// ---- block reductions (blockDim multiple of 64, <=1024) ----
__device__ inline void blk_reduce2(float& a, float& b, float* red) {
  #pragma unroll
  for (int off = 32; off > 0; off >>= 1) {
    a += __shfl_down(a, off, 64);
    b += __shfl_down(b, off, 64);
  }
  int w = threadIdx.x >> 6, lane = threadIdx.x & 63, nw = blockDim.x >> 6;
  __syncthreads();
  if (lane == 0) { red[w] = a; red[16 + w] = b; }
  __syncthreads();
  if (w == 0) {
    float sa = (lane < nw) ? red[lane] : 0.f;
    float sb = (lane < nw) ? red[16 + lane] : 0.f;
    #pragma unroll
    for (int off = 8; off > 0; off >>= 1) {
      sa += __shfl_down(sa, off, 64);
      sb += __shfl_down(sb, off, 64);
    }
    if (lane == 0) { red[32] = sa; red[33] = sb; }
  }
  __syncthreads();
  a = red[32]; b = red[33];
}

__device__ inline void blk_reduce1(float& a, float* red) {
  #pragma unroll
  for (int off = 32; off > 0; off >>= 1) a += __shfl_down(a, off, 64);
  int w = threadIdx.x >> 6, lane = threadIdx.x & 63, nw = blockDim.x >> 6;
  __syncthreads();
  if (lane == 0) red[w] = a;
  __syncthreads();
  if (w == 0) {
    float sa = (lane < nw) ? red[lane] : 0.f;
    #pragma unroll
    for (int off = 8; off > 0; off >>= 1) sa += __shfl_down(sa, off, 64);
    if (lane == 0) red[32] = sa;
  }
  __syncthreads();
  a = red[32];
}

// ---- K0: dtype flag detect + theta MLP + zero scalar accumulators ----
__global__ void k0_theta(const void* ste, const void* w1, const void* b1,
                         const void* w2, const void* b2, const void* gamma,
                         float* ws) {
  __shared__ int sflag;
  int tid = threadIdx.x;
  if (tid == 0) {
    unsigned bits = ((const unsigned*)gamma)[0];   // bn_gamma[0] == 1.0
    int f = (bits == 0x3F800000u) ? 0 : 1;         // 0x3F803F80 if bf16 pair
    sflag = f;
    ((int*)ws)[OF_FLAG] = f;
  }
  __syncthreads();
  int bf = sflag;
  if (tid < 264) {
    int b = tid / 66, r = tid % 66, o = r / 11, p = r % 11;
    // theta[b, o*11+p] = relu( b_t2[p] + sum_s w_t2[p,s] * (b_t1[o] + sum_t w_t1[o,t]*STE[b,t,s]) )
    float acc = ld_in(b2, p, bf);
    for (int s = 0; s < 10; ++s) {
      float h1 = ld_in(b1, o, bf);
      for (int t = 0; t < 5; ++t)
        h1 += ld_in(w1, o * 5 + t, bf) * ld_in(ste, (long)(b * 5 + t) * 10 + s, bf);
      acc += ld_in(w2, p * 10 + s, bf) * h1;
    }
    ws[OF_THETA + b * 66 + r] = fmaxf(acc, 0.f);
  }
  for (int q = tid; q < 2048; q += blockDim.x) ws[OF_SCAL + q] = 0.f;
}

// ---- convert sp/tp/x to f32 workspace ----
__global__ void k_conv(const void* x, const void* sp, const void* tp, float* ws) {
  int bf = ((const int*)ws)[0];
  long i = (long)blockIdx.x * blockDim.x + threadIdx.x;
  if (i < 262144L) ws[OF_SPF + i] = ld_in(sp, i, bf);
  else if (i < 266240L) ws[OF_TPF + (i - 262144L)] = ld_in(tp, i - 262144L, bf);
  else if (i < 2363392L) ws[OF_XF + (i - 266240L)] = ld_in(x, i - 266240L, bf);
}

// ---- per-slice 1/||x||_F ----
__global__ __launch_bounds__(1024) void k_nrm0(float* ws) {
  __shared__ float red[34];
  int slice = blockIdx.x, tid = threadIdx.x;
  const float* x = ws + OF_XF + (long)slice * 32768;
  float s = 0.f;
  #pragma unroll
  for (int k = 0; k < 32; ++k) { float v = x[k * 1024 + tid]; s += v * v; }
  blk_reduce1(s, red);
  if (tid == 0) ws[OF_SCAL + slice] = 1.f / fmaxf(sqrtf(s), EPS);
}

// ---- m00 = x * rinv0 ----
__global__ void k_scale(float* ws) {
  long e = (long)blockIdx.x * 1024 + threadIdx.x;
  ws[OF_MI0 + e] = ws[OF_XF + e] * ws[OF_SCAL + (e >> 15)];
}

// ---- K1a: rst[:,cols] = sp @ mhat_{i-1}[:,cols]; partial dots d1,d2 via atomics ----
// grid 512: slice = bid>>3, colblock cb = (bid>>1)&3, rowhalf rh = bid&1 ; 256 threads (1 row each)
__global__ __launch_bounds__(256) void k1a(float* ws, int i) {
  __shared__ float ldsT[16 * 516];   // mhat1 columns, transposed [tc][m], padded
  __shared__ float red[34];
  int bid = blockIdx.x, tid = threadIdx.x;
  int slice = bid >> 3, cb = (bid >> 1) & 3, rh = bid & 1;
  const float* spf = ws + OF_SPF;
  const float* prev1 = ws + OF_MI0 + ((long)(i - 1) * 64 + slice) * 32768;
  float rinv1 = 1.f, rinv2 = 1.f;
  if (i >= 2) rinv1 = 1.f / fmaxf(sqrtf(ws[OF_SCAL + 1344 + (i - 2) * 64 + slice]), EPS);
  const float* prev2 = ws + OF_MI0 + ((long)((i >= 2 ? i - 2 : 0)) * 64 + slice) * 32768;
  if (i >= 3) rinv2 = 1.f / fmaxf(sqrtf(ws[OF_SCAL + 1344 + (i - 3) * 64 + slice]), EPS);

  // stage normalized last_s columns (all 512 rows x 16 cols), transposed
  for (int q = 0; q < 32; ++q) {
    int e = q * 256 + tid;
    int m = e >> 4, tc = e & 15;
    ldsT[tc * 516 + m] = prev1[m * 64 + cb * 16 + tc] * rinv1;
  }
  __syncthreads();

  int n = rh * 256 + tid;
  const float4* sp4 = (const float4*)spf + (long)n * 128;
  const float4* lds4 = (const float4*)ldsT;   // row stride 129 float4s
  float r[16];
  #pragma unroll
  for (int tc = 0; tc < 16; ++tc) r[tc] = 0.f;
  #pragma unroll 2
  for (int m4 = 0; m4 < 128; ++m4) {
    float4 a = sp4[m4];
    #pragma unroll
    for (int tc = 0; tc < 16; ++tc) {
      float4 v = lds4[tc * 129 + m4];
      r[tc] += a.x * v.x + a.y * v.y + a.z * v.z + a.w * v.w;
    }
  }
  float d1p = 0.f, d2p = 0.f;
  float* rstp = ws + OF_RST + (long)slice * 32768;
  #pragma unroll
  for (int tc = 0; tc < 16; ++tc) {
    float rv = r[tc];
    d1p += rv * ldsT[tc * 516 + n];
    rstp[n * 64 + cb * 16 + tc] = rv;
  }
  if (i >= 2) {
    #pragma unroll
    for (int tc = 0; tc < 16; ++tc)
      d2p += r[tc] * prev2[n * 64 + cb * 16 + tc] * rinv2;
  }
  blk_reduce2(d1p, d2p, red);
  if (tid == 0) {
    atomicAdd(ws + OF_SCAL + 64 + (i - 1) * 64 + slice, d1p);
    if (i >= 2) atomicAdd(ws + OF_SCAL + 704 + (i - 1) * 64 + slice, d2p);
  }
}

// ---- K1b: v = rst - d1*mhat1 - d2*mhat2 ; store unnormalized v to mi0[i]; accumulate ||v||^2 ----
__global__ __launch_bounds__(1024) void k1b(float* ws, int i) {
  __shared__ float red[34];
  long e = (long)blockIdx.x * 1024 + threadIdx.x;
  int slice = (int)(e >> 15);
  float rinv1 = (i >= 2) ? 1.f / fmaxf(sqrtf(ws[OF_SCAL + 1344 + (i - 2) * 64 + slice]), EPS) : 1.f;
  float d1 = ws[OF_SCAL + 64 + (i - 1) * 64 + slice];
  float v = ws[OF_RST + e] - d1 * ws[OF_MI0 + (long)(i - 1) * 2097152 + e] * rinv1;
  if (i >= 2) {
    float rinv2 = (i >= 3) ? 1.f / fmaxf(sqrtf(ws[OF_SCAL + 1344 + (i - 3) * 64 + slice]), EPS) : 1.f;
    float d2 = ws[OF_SCAL + 704 + (i - 1) * 64 + slice];
    v -= d2 * ws[OF_MI0 + (long)(i - 2) * 2097152 + e] * rinv2;
  }
  ws[OF_MI0 + (long)i * 2097152 + e] = v;
  float np = v * v;
  blk_reduce1(np, red);
  if (threadIdx.x == 0) atomicAdd(ws + OF_SCAL + 1344 + (i - 1) * 64 + slice, np);
}

// ---- K2: one block per (slice, i): 5 t-basis steps, fully register-resident; writes partial x_st over seed ----
__global__ __launch_bounds__(1024) void k2(float* ws) {
  __shared__ float wlds[16 * 8 * 68];   // per-wave row chunks [wave][8 rows][64+pad]
  __shared__ float red[34];
  int bid = blockIdx.x, tid = threadIdx.x;
  int slice = bid / 11, ic = bid % 11;
  int b = slice >> 4;
  int w = tid >> 6, lane = tid & 63;
  const float* tpf = ws + OF_TPF;
  float tpc[64];                         // tp column for this lane: tpc[t] = tp[t][lane]
  #pragma unroll
  for (int t = 0; t < 64; ++t) tpc[t] = tpf[t * 64 + lane];

  float rinv = 1.f;
  if (ic >= 1) rinv = 1.f / fmaxf(sqrtf(ws[OF_SCAL + 1344 + (ic - 1) * 64 + slice]), EPS);
  float* seed = ws + OF_MI0 + (long)ic * 2097152 + (long)slice * 32768;
  float c0 = ws[OF_THETA + b * 66 + ic * 6 + 0];

  float last[32], sec[32], rst[32], acc[32];
  #pragma unroll
  for (int k = 0; k < 32; ++k) {
    float v = seed[k * 1024 + tid] * rinv;   // element (n = k*16+w, t = lane)
    last[k] = v; sec[k] = 0.f; acc[k] = c0 * v;
  }

  for (int j = 1; j <= 5; ++j) {
    float d1p = 0.f, d2p = 0.f;
    #pragma unroll
    for (int kc = 0; kc < 4; ++kc) {
      __syncthreads();
      #pragma unroll
      for (int kk = 0; kk < 8; ++kk)
        wlds[(w * 8 + kk) * 68 + lane] = last[kc * 8 + kk];
      __syncthreads();
      #pragma unroll
      for (int kk = 0; kk < 8; ++kk) {
        int k = kc * 8 + kk;
        const float4* row4 = (const float4*)(wlds + (w * 8 + kk) * 68);
        float f = 0.f;
        #pragma unroll
        for (int t4 = 0; t4 < 16; ++t4) {
          float4 v = row4[t4];   // broadcast read: whole row of last
          f += v.x * tpc[t4 * 4] + v.y * tpc[t4 * 4 + 1] + v.z * tpc[t4 * 4 + 2] + v.w * tpc[t4 * 4 + 3];
        }
        rst[k] = f;
        d1p += f * last[k];
        d2p += f * sec[k];
      }
    }
    blk_reduce2(d1p, d2p, red);
    float np = 0.f;
    #pragma unroll
    for (int k = 0; k < 32; ++k) {
      float v = rst[k] - d1p * last[k] - d2p * sec[k];
      rst[k] = v; np += v * v;
    }
    blk_reduce1(np, red);
    float ri = 1.f / fmaxf(sqrtf(np), EPS);
    float cj = ws[OF_THETA + b * 66 + ic * 6 + j];
    #pragma unroll
    for (int k = 0; k < 32; ++k) {
      float v = rst[k] * ri;
      acc[k] += cj * v;
      sec[k] = last[k];
      last[k] = v;
    }
  }
  #pragma unroll
  for (int k = 0; k < 32; ++k) seed[k * 1024 + tid] = acc[k];   // overwrite seed with partial x_st
}

// ---- K3: out = BN(MLP([x, x_st])) ----
__global__ __launch_bounds__(256) void k3(const void* wmlp, const void* bmlp,
    const void* gam, const void* bet, const void* mea, const void* var,
    const float* ws, void* out) {
  __shared__ float wA[64 * 16], wB[64 * 16], winv[64], wsh[64], wb[64];
  int tid = threadIdx.x;
  int bf = ((const int*)ws)[0];
  if (tid < 64) {
    float g = ld_in(gam, tid, bf), vv = ld_in(var, tid, bf);
    float iv = g / sqrtf(vv + 1e-5f);
    winv[tid] = iv;
    wsh[tid] = ld_in(bet, tid, bf) - ld_in(mea, tid, bf) * iv;
    wb[tid] = ld_in(bmlp, tid, bf);
  }
  for (int q = tid; q < 2048; q += 256) {
    int o = q >> 5, c = q & 31;
    float v = ld_in(wmlp, q, bf);
    if (c < 16) wA[o * 16 + c] = v; else wB[o * 16 + (c - 16)] = v;
  }
  __syncthreads();
  long g = (long)blockIdx.x * 256 + tid;
  int b = (int)(g >> 15); long pos = g & 32767;
  float xv[16], av[16];
  #pragma unroll
  for (int c = 0; c < 16; ++c)
    xv[c] = ws[OF_XF + ((long)(b * 16 + c)) * 32768 + pos];
  #pragma unroll
  for (int f = 0; f < 16; ++f) {
    float s = 0.f;
    #pragma unroll
    for (int i = 0; i < 11; ++i)
      s += ws[OF_MI0 + (long)i * 2097152 + ((long)(b * 16 + f)) * 32768 + pos];
    av[f] = s;
  }
  #pragma unroll 4
  for (int o = 0; o < 64; ++o) {
    float s = wb[o];
    #pragma unroll
    for (int c = 0; c < 16; ++c) s += wA[o * 16 + c] * xv[c];
    #pragma unroll
    for (int f = 0; f < 16; ++f) s += wB[o * 16 + f] * av[f];
    s = s * winv[o] + wsh[o];
    long oi = ((long)(b * 64 + o)) * 32768 + pos;
    if (bf) ((__hip_bfloat16*)out)[oi] = __float2bfloat16(s);
    else ((float*)out)[oi] = s;
  }
}

extern "C" void kernel_launch(void* const* d_in, const int* in_sizes, int n_in,
                              void* d_out, int out_size, void* d_ws, size_t ws_size,
                              hipStream_t stream) {
  (void)in_sizes; (void)n_in; (void)out_size; (void)ws_size;
  float* ws = (float*)d_ws;

  k0_theta<<<1, 320, 0, stream>>>(d_in[3], d_in[4], d_in[5], d_in[6], d_in[7], d_in[10], ws);
  k_conv<<<2308, 1024, 0, stream>>>(d_in[0], d_in[1], d_in[2], ws);
  k_nrm0<<<64, 1024, 0, stream>>>(ws);
  k_scale<<<2048, 1024, 0, stream>>>(ws);
  for (int i = 1; i <= 10; ++i) {
    k1a<<<512, 256, 0, stream>>>(ws, i);
    k1b<<<2048, 1024, 0, stream>>>(ws, i);
  }
  k2<<<704, 1024, 0, stream>>>(ws);
  k3<<<512, 256, 0, stream>>>(d_in[8], d_in[9], d_in[10], d_in[11], d_in[12], d_in[13],
                              ws, d_out);
}

// Round 2
// 1792.433 us; speedup vs baseline: 2.9031x; 2.9031x over previous
//
#include <hip/hip_runtime.h>
#include <hip/hip_bf16.h>

#define EPS 1e-8f

// ---- workspace layout (float offsets) ----
#define OF_FLAG   0L          // int flag: 0=f32 inputs, 1=bf16 inputs
#define OF_THETA  16L         // [B=4][66]
#define OF_TPF    512L        // tp as f32 [64][64]
#define OF_SPF    4608L       // sp as f32 [512][512]
#define OF_XF     266752L     // x as f32 [64][32768]
#define OF_MI0    2363904L    // [i=0..10][slice=0..63][32768]  (later overwritten with chain partial sums)
#define OF_SCAL   25432576L   // scalars: rinv0[64] @+0 ; d1 @+64+(i-1)*64 ; d2 @+704+... ; nrm @+1344+...
#define OF_RST    25434624L   // [64][32768] s-step matmul scratch
// total = 27531776 floats = 110.1 MB

__device__ inline float ld_in(const void* p, long i, int bf) {
  if (bf) return __bfloat162float(((const __hip_bfloat16*)p)[i]);
  return ((const float*)p)[i];
}

// ---- block reductions (blockDim multiple of 64, <=1024) ----
__device__ inline void blk_reduce2(float& a, float& b, float* red) {
  #pragma unroll
  for (int off = 32; off > 0; off >>= 1) {
    a += __shfl_down(a, off, 64);
    b += __shfl_down(b, off, 64);
  }
  int w = threadIdx.x >> 6, lane = threadIdx.x & 63, nw = blockDim.x >> 6;
  __syncthreads();
  if (lane == 0) { red[w] = a; red[16 + w] = b; }
  __syncthreads();
  if (w == 0) {
    float sa = (lane < nw) ? red[lane] : 0.f;
    float sb = (lane < nw) ? red[16 + lane] : 0.f;
    #pragma unroll
    for (int off = 8; off > 0; off >>= 1) {
      sa += __shfl_down(sa, off, 64);
      sb += __shfl_down(sb, off, 64);
    }
    if (lane == 0) { red[32] = sa; red[33] = sb; }
  }
  __syncthreads();
  a = red[32]; b = red[33];
}

__device__ inline void blk_reduce1(float& a, float* red) {
  #pragma unroll
  for (int off = 32; off > 0; off >>= 1) a += __shfl_down(a, off, 64);
  int w = threadIdx.x >> 6, lane = threadIdx.x & 63, nw = blockDim.x >> 6;
  __syncthreads();
  if (lane == 0) red[w] = a;
  __syncthreads();
  if (w == 0) {
    float sa = (lane < nw) ? red[lane] : 0.f;
    #pragma unroll
    for (int off = 8; off > 0; off >>= 1) sa += __shfl_down(sa, off, 64);
    if (lane == 0) red[32] = sa;
  }
  __syncthreads();
  a = red[32];
}

// ---- K0: dtype flag detect + theta MLP + zero scalar accumulators ----
__global__ void k0_theta(const void* ste, const void* w1, const void* b1,
                         const void* w2, const void* b2, const void* gamma,
                         float* ws) {
  __shared__ int sflag;
  int tid = threadIdx.x;
  if (tid == 0) {
    unsigned bits = ((const unsigned*)gamma)[0];   // bn_gamma[0] == 1.0
    int f = (bits == 0x3F800000u) ? 0 : 1;         // 0x3F803F80 if bf16 pair
    sflag = f;
    ((int*)ws)[OF_FLAG] = f;
  }
  __syncthreads();
  int bf = sflag;
  if (tid < 264) {
    int b = tid / 66, r = tid % 66, o = r / 11, p = r % 11;
    float acc = ld_in(b2, p, bf);
    for (int s = 0; s < 10; ++s) {
      float h1 = ld_in(b1, o, bf);
      for (int t = 0; t < 5; ++t)
        h1 += ld_in(w1, o * 5 + t, bf) * ld_in(ste, (long)(b * 5 + t) * 10 + s, bf);
      acc += ld_in(w2, p * 10 + s, bf) * h1;
    }
    ws[OF_THETA + b * 66 + r] = fmaxf(acc, 0.f);
  }
  for (int q = tid; q < 2048; q += blockDim.x) ws[OF_SCAL + q] = 0.f;
}

// ---- convert sp/tp/x to f32 workspace ----
__global__ void k_conv(const void* x, const void* sp, const void* tp, float* ws) {
  int bf = ((const int*)ws)[0];
  long i = (long)blockIdx.x * blockDim.x + threadIdx.x;
  if (i < 262144L) ws[OF_SPF + i] = ld_in(sp, i, bf);
  else if (i < 266240L) ws[OF_TPF + (i - 262144L)] = ld_in(tp, i - 262144L, bf);
  else if (i < 2363392L) ws[OF_XF + (i - 266240L)] = ld_in(x, i - 266240L, bf);
}

// ---- per-slice 1/||x||_F ----
__global__ __launch_bounds__(1024) void k_nrm0(float* ws) {
  __shared__ float red[34];
  int slice = blockIdx.x, tid = threadIdx.x;
  const float* x = ws + OF_XF + (long)slice * 32768;
  float s = 0.f;
  #pragma unroll
  for (int k = 0; k < 32; ++k) { float v = x[k * 1024 + tid]; s += v * v; }
  blk_reduce1(s, red);
  if (tid == 0) ws[OF_SCAL + slice] = 1.f / fmaxf(sqrtf(s), EPS);
}

// ---- m00 = x * rinv0 ----
__global__ void k_scale(float* ws) {
  long e = (long)blockIdx.x * 1024 + threadIdx.x;
  ws[OF_MI0 + e] = ws[OF_XF + e] * ws[OF_SCAL + (e >> 15)];
}

// ---- K1a: rst[:,cols] = sp @ mhat_{i-1}[:,cols]; partial dots d1,d2 via atomics ----
__global__ __launch_bounds__(256) void k1a(float* ws, int i) {
  __shared__ float ldsT[16 * 516];   // mhat1 columns, transposed [tc][m], padded
  __shared__ float red[34];
  int bid = blockIdx.x, tid = threadIdx.x;
  int slice = bid >> 3, cb = (bid >> 1) & 3, rh = bid & 1;
  const float* spf = ws + OF_SPF;
  const float* prev1 = ws + OF_MI0 + ((long)(i - 1) * 64 + slice) * 32768;
  float rinv1 = 1.f, rinv2 = 1.f;
  if (i >= 2) rinv1 = 1.f / fmaxf(sqrtf(ws[OF_SCAL + 1344 + (i - 2) * 64 + slice]), EPS);
  const float* prev2 = ws + OF_MI0 + ((long)((i >= 2 ? i - 2 : 0)) * 64 + slice) * 32768;
  if (i >= 3) rinv2 = 1.f / fmaxf(sqrtf(ws[OF_SCAL + 1344 + (i - 3) * 64 + slice]), EPS);

  for (int q = 0; q < 32; ++q) {
    int e = q * 256 + tid;
    int m = e >> 4, tc = e & 15;
    ldsT[tc * 516 + m] = prev1[m * 64 + cb * 16 + tc] * rinv1;
  }
  __syncthreads();

  int n = rh * 256 + tid;
  const float4* sp4 = (const float4*)spf + (long)n * 128;
  const float4* lds4 = (const float4*)ldsT;   // row stride 129 float4s
  float r[16];
  #pragma unroll
  for (int tc = 0; tc < 16; ++tc) r[tc] = 0.f;
  #pragma unroll 2
  for (int m4 = 0; m4 < 128; ++m4) {
    float4 a = sp4[m4];
    #pragma unroll
    for (int tc = 0; tc < 16; ++tc) {
      float4 v = lds4[tc * 129 + m4];
      r[tc] += a.x * v.x + a.y * v.y + a.z * v.z + a.w * v.w;
    }
  }
  float d1p = 0.f, d2p = 0.f;
  float* rstp = ws + OF_RST + (long)slice * 32768;
  #pragma unroll
  for (int tc = 0; tc < 16; ++tc) {
    float rv = r[tc];
    d1p += rv * ldsT[tc * 516 + n];
    rstp[n * 64 + cb * 16 + tc] = rv;
  }
  if (i >= 2) {
    #pragma unroll
    for (int tc = 0; tc < 16; ++tc)
      d2p += r[tc] * prev2[n * 64 + cb * 16 + tc] * rinv2;
  }
  blk_reduce2(d1p, d2p, red);
  if (tid == 0) {
    atomicAdd(ws + OF_SCAL + 64 + (i - 1) * 64 + slice, d1p);
    if (i >= 2) atomicAdd(ws + OF_SCAL + 704 + (i - 1) * 64 + slice, d2p);
  }
}

// ---- K1b: v = rst - d1*mhat1 - d2*mhat2 ; store unnormalized v; accumulate ||v||^2 ----
__global__ __launch_bounds__(1024) void k1b(float* ws, int i) {
  __shared__ float red[34];
  long e = (long)blockIdx.x * 1024 + threadIdx.x;
  int slice = (int)(e >> 15);
  float rinv1 = (i >= 2) ? 1.f / fmaxf(sqrtf(ws[OF_SCAL + 1344 + (i - 2) * 64 + slice]), EPS) : 1.f;
  float d1 = ws[OF_SCAL + 64 + (i - 1) * 64 + slice];
  float v = ws[OF_RST + e] - d1 * ws[OF_MI0 + (long)(i - 1) * 2097152 + e] * rinv1;
  if (i >= 2) {
    float rinv2 = (i >= 3) ? 1.f / fmaxf(sqrtf(ws[OF_SCAL + 1344 + (i - 3) * 64 + slice]), EPS) : 1.f;
    float d2 = ws[OF_SCAL + 704 + (i - 1) * 64 + slice];
    v -= d2 * ws[OF_MI0 + (long)(i - 2) * 2097152 + e] * rinv2;
  }
  ws[OF_MI0 + (long)i * 2097152 + e] = v;
  float np = v * v;
  blk_reduce1(np, red);
  if (threadIdx.x == 0) atomicAdd(ws + OF_SCAL + 1344 + (i - 1) * 64 + slice, np);
}

// ---- K2 v2: one block per (slice, i). State: last in LDS (wave-local rows),
//      f/sec/acc in registers (96 VGPR). tp column hoisted per-u4 from LDS.
__global__ __launch_bounds__(1024, 4) void k2(float* ws) {
  __shared__ float lastL[32768];     // element (n=k*16+w, t=lane) at [k*1024 + tid]
  __shared__ float tpT[64 * 68];     // tpT[t][u] = tp[u][t], padded
  __shared__ float red[34];
  int tid = threadIdx.x;
  int slice = blockIdx.x / 11, ic = blockIdx.x % 11;
  int b = slice >> 4;
  int w = tid >> 6, lane = tid & 63;

  // stage tp transposed
  for (int q = tid; q < 4096; q += 1024) {
    int u = q >> 6, t = q & 63;
    tpT[t * 68 + u] = ws[OF_TPF + q];
  }

  float rinv = 1.f;
  if (ic >= 1) rinv = 1.f / fmaxf(sqrtf(ws[OF_SCAL + 1344 + (ic - 1) * 64 + slice]), EPS);
  float* seed = ws + OF_MI0 + (long)ic * 2097152 + (long)slice * 32768;
  float c0 = ws[OF_THETA + b * 66 + ic * 6 + 0];

  float f[32], sec[32], acc[32];
  #pragma unroll
  for (int k = 0; k < 32; ++k) {
    float v = seed[k * 1024 + tid] * rinv;
    lastL[k * 1024 + tid] = v;
    sec[k] = 0.f;
    acc[k] = c0 * v;
  }
  __syncthreads();   // tpT (and lastL) visible

  const float* rowbase = lastL + w * 64;   // row r=k*16+w starts at k*1024 + w*64

  for (int j = 1; j <= 5; ++j) {
    // ---- matmul: f[k] = sum_u last[row_k][u] * tp[u][lane], tp chunk hoisted ----
    #pragma unroll
    for (int k = 0; k < 32; ++k) f[k] = 0.f;
    for (int u4 = 0; u4 < 16; ++u4) {
      float4 t4 = *(const float4*)(tpT + lane * 68 + u4 * 4);
      #pragma unroll
      for (int k = 0; k < 32; ++k) {
        float4 r4 = *(const float4*)(rowbase + k * 1024 + u4 * 4);  // broadcast
        f[k] += r4.x * t4.x + r4.y * t4.y + r4.z * t4.z + r4.w * t4.w;
      }
    }
    float d1p = 0.f, d2p = 0.f;
    #pragma unroll
    for (int k = 0; k < 32; ++k) {
      float lv = lastL[k * 1024 + tid];
      d1p += f[k] * lv;
      d2p += f[k] * sec[k];
    }
    blk_reduce2(d1p, d2p, red);
    float np = 0.f;
    #pragma unroll
    for (int k = 0; k < 32; ++k) {
      float lv = lastL[k * 1024 + tid];
      float v = f[k] - d1p * lv - d2p * sec[k];
      f[k] = v;
      sec[k] = lv;          // old last becomes new sec
      np += v * v;
    }
    blk_reduce1(np, red);   // after this, all lastL reads for this step are done
    float ri = 1.f / fmaxf(sqrtf(np), EPS);
    float cj = ws[OF_THETA + b * 66 + ic * 6 + j];
    #pragma unroll
    for (int k = 0; k < 32; ++k) {
      float vh = f[k] * ri;
      acc[k] += cj * vh;
      lastL[k * 1024 + tid] = vh;   // wave-local: no barrier needed before next matmul
    }
  }
  #pragma unroll
  for (int k = 0; k < 32; ++k) seed[k * 1024 + tid] = acc[k];
}

// ---- K3: out = BN(MLP([x, x_st])) ----
__global__ __launch_bounds__(256) void k3(const void* wmlp, const void* bmlp,
    const void* gam, const void* bet, const void* mea, const void* var,
    const float* ws, void* out) {
  __shared__ float wA[64 * 16], wB[64 * 16], winv[64], wsh[64], wb[64];
  int tid = threadIdx.x;
  int bf = ((const int*)ws)[0];
  if (tid < 64) {
    float g = ld_in(gam, tid, bf), vv = ld_in(var, tid, bf);
    float iv = g / sqrtf(vv + 1e-5f);
    winv[tid] = iv;
    wsh[tid] = ld_in(bet, tid, bf) - ld_in(mea, tid, bf) * iv;
    wb[tid] = ld_in(bmlp, tid, bf);
  }
  for (int q = tid; q < 2048; q += 256) {
    int o = q >> 5, c = q & 31;
    float v = ld_in(wmlp, q, bf);
    if (c < 16) wA[o * 16 + c] = v; else wB[o * 16 + (c - 16)] = v;
  }
  __syncthreads();
  long g = (long)blockIdx.x * 256 + tid;
  int b = (int)(g >> 15); long pos = g & 32767;
  float xv[16], av[16];
  #pragma unroll
  for (int c = 0; c < 16; ++c)
    xv[c] = ws[OF_XF + ((long)(b * 16 + c)) * 32768 + pos];
  #pragma unroll
  for (int f = 0; f < 16; ++f) {
    float s = 0.f;
    #pragma unroll
    for (int i = 0; i < 11; ++i)
      s += ws[OF_MI0 + (long)i * 2097152 + ((long)(b * 16 + f)) * 32768 + pos];
    av[f] = s;
  }
  #pragma unroll 4
  for (int o = 0; o < 64; ++o) {
    float s = wb[o];
    #pragma unroll
    for (int c = 0; c < 16; ++c) s += wA[o * 16 + c] * xv[c];
    #pragma unroll
    for (int f = 0; f < 16; ++f) s += wB[o * 16 + f] * av[f];
    s = s * winv[o] + wsh[o];
    long oi = ((long)(b * 64 + o)) * 32768 + pos;
    if (bf) ((__hip_bfloat16*)out)[oi] = __float2bfloat16(s);
    else ((float*)out)[oi] = s;
  }
}

extern "C" void kernel_launch(void* const* d_in, const int* in_sizes, int n_in,
                              void* d_out, int out_size, void* d_ws, size_t ws_size,
                              hipStream_t stream) {
  (void)in_sizes; (void)n_in; (void)out_size; (void)ws_size;
  float* ws = (float*)d_ws;

  k0_theta<<<1, 320, 0, stream>>>(d_in[3], d_in[4], d_in[5], d_in[6], d_in[7], d_in[10], ws);
  k_conv<<<2308, 1024, 0, stream>>>(d_in[0], d_in[1], d_in[2], ws);
  k_nrm0<<<64, 1024, 0, stream>>>(ws);
  k_scale<<<2048, 1024, 0, stream>>>(ws);
  for (int i = 1; i <= 10; ++i) {
    k1a<<<512, 256, 0, stream>>>(ws, i);
    k1b<<<2048, 1024, 0, stream>>>(ws, i);
  }
  k2<<<704, 1024, 0, stream>>>(ws);
  k3<<<512, 256, 0, stream>>>(d_in[8], d_in[9], d_in[10], d_in[11], d_in[12], d_in[13],
                              ws, d_out);
}